// Round 6
// baseline (6032.066 us; speedup 1.0000x reference)
//
#include <hip/hip_runtime.h>
#include <cstdint>

typedef unsigned short u16;
typedef __attribute__((ext_vector_type(4))) float f32x4;
typedef __attribute__((ext_vector_type(8))) short bf16x8;   // 8 bf16 in 4 VGPRs
typedef __attribute__((ext_vector_type(4))) u16 u16x4;

constexpr int NB = 1024;   // batch
constexpr int NT = 200;    // time
constexpr int ND = 128;    // input dim
constexpr int NU = 128;    // units
constexpr int NG = 512;    // 4*U gates
constexpr int ROWS = 16;   // batch rows per block (MFMA M)
constexpr int AK = 512;    // A-tile k extent: [xhi|xlo|hhi|hlo] x 128
constexpr int ABUF = ROWS * AK;           // 8192 u16 per buffer
constexpr int LDS_A_ELEMS  = 2 * ABUF;    // double-buffered: 16384 u16 = 32 KiB

__device__ __forceinline__ u16 f2bf(float x) {
    uint32_t u = __builtin_bit_cast(uint32_t, x);
    u = (u + 0x7fffu + ((u >> 16) & 1u)) >> 16;   // RNE
    return (u16)u;
}
__device__ __forceinline__ float bf2f(u16 b) {
    uint32_t u = ((uint32_t)b) << 16;
    return __builtin_bit_cast(float, u);
}
__device__ __forceinline__ float sigm(float x) {
    return __builtin_amdgcn_rcpf(1.f + __expf(-x));
}
__device__ __forceinline__ float tanh_fast(float x) {
    float e = __expf(-2.f * fabsf(x));
    float t = (1.f - e) * __builtin_amdgcn_rcpf(1.f + e);
    return copysignf(t, x);
}

// One LSTM layer scan for 16 batch rows. All weight splits (Wk hi/lo, Wr
// hi/lo) live in registers (unified VGPR/AGPR file, ~400/wave incl. accs);
// LDS holds only the double-buffered A-tile (x and h, each hi+lo bf16).
// Exactly ONE __syncthreads() per step.
__device__ __forceinline__ void run_layer(
    const float* __restrict__ Wk, const float* __restrict__ Wr,
    const float* __restrict__ Bv,
    const float* __restrict__ src, float* __restrict__ dst,
    u16* A, const int dir, const int base_b,
    const int tid, const int q, const int cl, const int uu,
    const int sr, const int sc)
{
    __syncthreads();   // prior layer's LDS reads done, its global stores drained

    // ---- resident weight fragments (B-side): Wk hi/lo, Wr hi/lo
    bf16x8 wkh[4][4], wkl[4][4], wrh[4][4], wrl[4][4];
    #pragma unroll
    for (int g = 0; g < 4; ++g) {
        const int col = g * NU + uu;
        #pragma unroll
        for (int s = 0; s < 4; ++s) {
            bf16x8 kh, kl, rh, rl;
            #pragma unroll
            for (int j = 0; j < 8; ++j) {
                const int k = s * 32 + q * 8 + j;
                const float wk = Wk[k * NG + col];
                const u16 khi = f2bf(wk);
                kh[j] = (short)khi;
                kl[j] = (short)f2bf(wk - bf2f(khi));
                const float wr = Wr[k * NG + col];
                const u16 rhi = f2bf(wr);
                rh[j] = (short)rhi;
                rl[j] = (short)f2bf(wr - bf2f(rhi));
            }
            wkh[g][s] = kh; wkl[g][s] = kl; wrh[g][s] = rh; wrl[g][s] = rl;
        }
    }
    float bias[4];
    #pragma unroll
    for (int g = 0; g < 4; ++g) bias[g] = Bv[g * NU + uu];

    for (int i = tid; i < LDS_A_ELEMS; i += 512) A[i] = 0;   // h planes must be 0
    f32x4 cc = {0.f, 0.f, 0.f, 0.f};

    const size_t srow = (size_t)(base_b + sr) * (NT * NU) + sc;
    const uint32_t stg = (uint32_t)(sr * 1024 + ((2 * sc) ^ ((sr & 15) << 4))) >> 1;

    __syncthreads();   // zeroing complete before prologue staging

    // prologue: stage x0 into buffer 0; hold x1 in regs
    {
        const float4 v = *(const float4*)&src[srow + (size_t)(dir ? NT - 1 : 0) * NU];
        const float vv[4] = {v.x, v.y, v.z, v.w};
        u16x4 hi4, lo4;
        #pragma unroll
        for (int e = 0; e < 4; ++e) {
            const u16 h = f2bf(vv[e]);
            hi4[e] = h;
            lo4[e] = f2bf(vv[e] - bf2f(h));
        }
        *(u16x4*)&A[stg]       = hi4;
        *(u16x4*)&A[stg + 128] = lo4;
    }
    float4 nxt = *(const float4*)&src[srow + (size_t)(dir ? NT - 2 : 1) * NU];
    __syncthreads();   // staging visible

    int p = 0;
    for (int step = 0; step < NT; ++step) {
        const int t = dir ? (NT - 1 - step) : step;

        // ---- prefetch x_{t+2} FIRST: ~2 steps of cover before its use/drain
        float4 fut;
        if (step + 2 < NT) {
            const int tf = dir ? (NT - 3 - step) : (step + 2);
            fut = *(const float4*)&src[srow + (size_t)tf * NU];
        }

        const u16* Ard = A + p * ABUF;
        u16*       Awr = A + (p ^ 1) * ABUF;

        // split accumulator chains (depth 6 instead of 12): [g][s01|s23]
        f32x4 ax0[4], ax1[4], ah0[4], ah1[4];
        #pragma unroll
        for (int g = 0; g < 4; ++g) {
            ax0[g] = (f32x4){bias[g], bias[g], bias[g], bias[g]};
            ax1[g] = (f32x4){0.f, 0.f, 0.f, 0.f};
            ah0[g] = (f32x4){0.f, 0.f, 0.f, 0.f};
            ah1[g] = (f32x4){0.f, 0.f, 0.f, 0.f};
        }

        #pragma unroll
        for (int s = 0; s < 4; ++s) {
            const uint32_t ab =
                (uint32_t)(cl * 1024 + ((s * 64 + q * 16) ^ ((cl & 15) << 4)));
            const bf16x8 axh = *(const bf16x8*)&Ard[(ab >> 1)];
            const bf16x8 axl = *(const bf16x8*)&Ard[(ab >> 1) + 128];
            const bf16x8 ahh = *(const bf16x8*)&Ard[(ab >> 1) + 256];
            const bf16x8 ahl = *(const bf16x8*)&Ard[(ab >> 1) + 384];
            #pragma unroll
            for (int g = 0; g < 4; ++g) {
                f32x4* px = (s < 2) ? &ax0[g] : &ax1[g];
                f32x4* ph = (s < 2) ? &ah0[g] : &ah1[g];
                *px = __builtin_amdgcn_mfma_f32_16x16x32_bf16(axh, wkh[g][s], *px, 0, 0, 0);
                *px = __builtin_amdgcn_mfma_f32_16x16x32_bf16(axl, wkh[g][s], *px, 0, 0, 0);
                *px = __builtin_amdgcn_mfma_f32_16x16x32_bf16(axh, wkl[g][s], *px, 0, 0, 0);
                *ph = __builtin_amdgcn_mfma_f32_16x16x32_bf16(ahh, wrh[g][s], *ph, 0, 0, 0);
                *ph = __builtin_amdgcn_mfma_f32_16x16x32_bf16(ahl, wrh[g][s], *ph, 0, 0, 0);
                *ph = __builtin_amdgcn_mfma_f32_16x16x32_bf16(ahh, wrl[g][s], *ph, 0, 0, 0);
            }
        }

        // gates + state; C/D layout: col = lane&15 (unit), row = q*4+j (batch row)
        float hv[4];
        #pragma unroll
        for (int j = 0; j < 4; ++j) {
            const float gi = sigm(ax0[0][j] + ax1[0][j] + ah0[0][j] + ah1[0][j]);
            const float gf = sigm(ax0[1][j] + ax1[1][j] + ah0[1][j] + ah1[1][j]);
            const float gg = tanh_fast(ax0[2][j] + ax1[2][j] + ah0[2][j] + ah1[2][j]);
            const float go = sigm(ax0[3][j] + ax1[3][j] + ah0[3][j] + ah1[3][j]);
            const float cn = gf * cc[j] + gi * gg;
            cc[j] = cn;
            hv[j] = go * tanh_fast(cn);
        }
        // dst stores issue ASAP after h: max distance to the barrier drain
        #pragma unroll
        for (int j = 0; j < 4; ++j) {
            const int r = q * 4 + j;
            dst[(size_t)(base_b + r) * (NT * NU) + (size_t)t * NU + uu] = hv[j];
        }
        #pragma unroll
        for (int j = 0; j < 4; ++j) {
            const int r = q * 4 + j;
            const u16 hh = f2bf(hv[j]);
            const u16 hl = f2bf(hv[j] - bf2f(hh));
            const uint32_t hb = (uint32_t)(r * 1024 + ((2 * uu) ^ ((r & 15) << 4)));
            Awr[(hb >> 1) + 256] = hh;   // h_hi plane of the NEXT-step buffer
            Awr[(hb >> 1) + 384] = hl;   // h_lo plane
        }

        // stage x_{t+1} (loaded 1-2 steps ago) into the next-step buffer
        if (step + 1 < NT) {
            const float vv[4] = {nxt.x, nxt.y, nxt.z, nxt.w};
            u16x4 hi4, lo4;
            #pragma unroll
            for (int e = 0; e < 4; ++e) {
                const u16 h = f2bf(vv[e]);
                hi4[e] = h;
                lo4[e] = f2bf(vv[e] - bf2f(h));
            }
            *(u16x4*)&Awr[stg]       = hi4;
            *(u16x4*)&Awr[stg + 128] = lo4;
            nxt = fut;
        }

        __syncthreads();   // the ONLY per-step barrier
        p ^= 1;
    }
}

__global__ __launch_bounds__(512, 2)
void lstm_scan(const float* __restrict__ x,
               const float* __restrict__ fwk, const float* __restrict__ fwrk,
               const float* __restrict__ fwb,
               const float* __restrict__ bwk, const float* __restrict__ bwrk,
               const float* __restrict__ bwb,
               float* __restrict__ buf_fw, float* __restrict__ buf_bw) {
    __shared__ __align__(16) u16 A[LDS_A_ELEMS];   // 2 x [16][512] bf16, swizzled

    const int tid  = threadIdx.x;
    const int lane = tid & 63;
    const int wv   = tid >> 6;          // wave 0..7
    const int dir  = blockIdx.y;        // 0 = fw, 1 = bw
    const int base_b = blockIdx.x * ROWS;

    const float* kp = dir ? bwk  : fwk;
    const float* rp = dir ? bwrk : fwrk;
    const float* bp = dir ? bwb  : fwb;
    float* buf = dir ? buf_bw : buf_fw;

    const int q  = lane >> 4;           // k-group 0..3
    const int cl = lane & 15;           // A-row / B-col within tile
    const int uu = (wv << 4) + cl;      // unit 0..127 owned by this lane

    const int sr = tid >> 5;            // staging row 0..15
    const int sc = (tid & 31) << 2;     // staging col 0..124

    // layer 0: input x
    run_layer(kp, rp, bp, x, buf, A, dir, base_b, tid, q, cl, uu, sr, sc);
    // layer 1: input = layer-0 h sequence (in-place)
    run_layer(kp + ND * NG, rp + NU * NG, bp + NG, buf, buf, A,
              dir, base_b, tid, q, cl, uu, sr, sc);
}

// ---- merge: out = 0.5*(fw + bw) ---------------------------------------------
__global__ void merge_out(const float* __restrict__ a, const float* __restrict__ b,
                          float* __restrict__ o, int nvec) {
    int i = blockIdx.x * blockDim.x + threadIdx.x;
    const int st = gridDim.x * blockDim.x;
    for (; i < nvec; i += st) {
        const float4 va = ((const float4*)a)[i];
        const float4 vb = ((const float4*)b)[i];
        float4 r;
        r.x = 0.5f * (va.x + vb.x);
        r.y = 0.5f * (va.y + vb.y);
        r.z = 0.5f * (va.z + vb.z);
        r.w = 0.5f * (va.w + vb.w);
        ((float4*)o)[i] = r;
    }
}

extern "C" void kernel_launch(void* const* d_in, const int* in_sizes, int n_in,
                              void* d_out, int out_size, void* d_ws, size_t ws_size,
                              hipStream_t stream) {
    const float* x    = (const float*)d_in[0];
    const float* fwk  = (const float*)d_in[1];
    const float* fwrk = (const float*)d_in[2];
    const float* fwb  = (const float*)d_in[3];
    const float* bwk  = (const float*)d_in[4];
    const float* bwrk = (const float*)d_in[5];
    const float* bwb  = (const float*)d_in[6];
    float* out = (float*)d_out;

    const size_t seq = (size_t)NB * NT * NU;     // 26,214,400 elements
    float* buf_fw = (float*)d_ws;                // fw h-sequence fp32 (l0 then l1 in-place)
    float* buf_bw = buf_fw + seq;                // bw h-sequence fp32

    lstm_scan<<<dim3(NB / ROWS, 2), 512, 0, stream>>>(
        x, fwk, fwrk, fwb, bwk, bwrk, bwb, buf_fw, buf_bw);

    const int nvec = (int)(seq / 4);
    merge_out<<<2048, 256, 0, stream>>>(buf_fw, buf_bw, out, nvec);
}

// Round 7
// 2642.957 us; speedup vs baseline: 2.2823x; 2.2823x over previous
//
#include <hip/hip_runtime.h>
#include <cstdint>

typedef unsigned short u16;
typedef __attribute__((ext_vector_type(4))) float f32x4;
typedef __attribute__((ext_vector_type(8))) short bf16x8;   // 8 bf16 in 4 VGPRs
typedef __attribute__((ext_vector_type(4))) u16 u16x4;

constexpr int NB = 1024;   // batch
constexpr int NT = 200;    // time
constexpr int ND = 128;    // input dim
constexpr int NU = 128;    // units
constexpr int NG = 512;    // 4*U gates
constexpr int ROWS = 16;   // batch rows per block (MFMA M)
constexpr int LDS_A_ELEMS  = ROWS * 512;  // 8192 u16 = 16 KiB (single A buffer, r3 scheme)
constexpr int LDS_WK_ELEMS = NG * ND;     // 65536 u16 = 128 KiB (Wk_lo, [col][k])

__device__ __forceinline__ u16 f2bf(float x) {
    uint32_t u = __builtin_bit_cast(uint32_t, x);
    u = (u + 0x7fffu + ((u >> 16) & 1u)) >> 16;   // RNE
    return (u16)u;
}
__device__ __forceinline__ float bf2f(u16 b) {
    uint32_t u = ((uint32_t)b) << 16;
    return __builtin_bit_cast(float, u);
}
__device__ __forceinline__ float sigm(float x) {
    return __builtin_amdgcn_rcpf(1.f + __expf(-x));
}
__device__ __forceinline__ float tanh_fast(float x) {
    float e = __expf(-2.f * fabsf(x));
    float t = (1.f - e) * __builtin_amdgcn_rcpf(1.f + e);
    return copysignf(t, x);
}

__device__ __forceinline__ void spin_until(const int* p, int need) {
    while (__hip_atomic_load(p, __ATOMIC_ACQUIRE, __HIP_MEMORY_SCOPE_AGENT) < need)
        __builtin_amdgcn_s_sleep(2);
}

// One LSTM layer scan for 16 batch rows (r3-proven core: 3 register weight
// arrays wkh/wrh/wrl — the compiler AGPR-hosts exactly 3, a 4th forces
// global rematerialization (r6: FETCH 25x) — plus Wk_lo in LDS).
// PROD: publish per-step progress (layer 0). CONS: gate x-loads on the
// producer's progress (layer 1). Chains (dir,group) are independent.
template<bool PROD, bool CONS>
__device__ __forceinline__ void run_layer(
    const float* __restrict__ Wk, const float* __restrict__ Wr,
    const float* __restrict__ Bv,
    const float* __restrict__ src, float* __restrict__ dst,
    u16* A, u16* WKLO, int* prog_c,
    const int dir, const int base_b,
    const int tid, const int q, const int cl, const int uu,
    const int sr, const int sc)
{
    // ---- resident weight fragments (B-side): Wk_hi, Wr_hi, Wr_lo
    bf16x8 wkh[4][4], wrh[4][4], wrl[4][4];
    #pragma unroll
    for (int g = 0; g < 4; ++g) {
        const int col = g * NU + uu;
        #pragma unroll
        for (int s = 0; s < 4; ++s) {
            bf16x8 fa, fh, fl;
            #pragma unroll
            for (int j = 0; j < 8; ++j) {
                const int k = s * 32 + q * 8 + j;
                fa[j] = (short)f2bf(Wk[k * NG + col]);
                const float w = Wr[k * NG + col];
                const u16 hi = f2bf(w);
                fh[j] = (short)hi;
                fl[j] = (short)f2bf(w - bf2f(hi));
            }
            wkh[g][s] = fa; wrh[g][s] = fh; wrl[g][s] = fl;
        }
    }
    float bias[4];
    #pragma unroll
    for (int g = 0; g < 4; ++g) bias[g] = Bv[g * NU + uu];

    // fill Wk_lo into LDS (transposed [col][k], swizzled)
    for (int idx = tid; idx < LDS_WK_ELEMS; idx += 512) {
        const int col = idx & (NG - 1);
        const int k   = idx >> 9;
        const float w = Wk[k * NG + col];
        const float lo = w - bf2f(f2bf(w));
        WKLO[(uint32_t)(col * 256 + ((2 * k) ^ ((col & 15) << 4))) >> 1] = f2bf(lo);
    }
    for (int i = tid; i < LDS_A_ELEMS; i += 512) A[i] = 0;   // h planes must be 0
    f32x4 cc = {0.f, 0.f, 0.f, 0.f};

    const size_t srow = (size_t)(base_b + sr) * (NT * NU) + sc;

    if (CONS) spin_until(prog_c, 1);   // x_{t(0)} available
    float4 cur = *(const float4*)&src[srow + (size_t)(dir ? NT - 1 : 0) * NU];
    __syncthreads();   // WKLO fill + A zero complete (before in-loop staging)

    for (int step = 0; step < NT; ++step) {
        const int t = dir ? (NT - 1 - step) : step;

        // ---- stage x_t (in regs) as hi+lo into A's k<256 half
        {
            const float vv[4] = {cur.x, cur.y, cur.z, cur.w};
            u16x4 hi4, lo4;
            #pragma unroll
            for (int e = 0; e < 4; ++e) {
                const u16 h = f2bf(vv[e]);
                hi4[e] = h;
                lo4[e] = f2bf(vv[e] - bf2f(h));
            }
            const uint32_t b0 = (uint32_t)(sr * 1024 + ((2 * sc) ^ ((sr & 15) << 4)));
            *(u16x4*)&A[(b0 >> 1)]       = hi4;   // x_hi: k in [0,128)
            *(u16x4*)&A[(b0 >> 1) + 128] = lo4;   // x_lo: k in [128,256)
        }
        __syncthreads();   // sync1: staging visible; all waves' step-(s-1) stores drained

        // publish: steps 0..step-1 fully stored (vmcnt drained by sync1 above)
        if (PROD && tid == 0)
            __hip_atomic_store(prog_c, step, __ATOMIC_RELEASE, __HIP_MEMORY_SCOPE_AGENT);

        // gate + prefetch x_{t(step+1)}: used at next step's staging
        if (step + 1 < NT) {
            if (CONS) spin_until(prog_c, (step + 2 < NT) ? step + 2 : NT);
            const int tn = dir ? (NT - 2 - step) : (step + 1);
            cur = *(const float4*)&src[srow + (size_t)tn * NU];
        }

        f32x4 accx[4], acch[4];   // x-side (carries bias) and h-side chains
        #pragma unroll
        for (int g = 0; g < 4; ++g) {
            accx[g] = (f32x4){bias[g], bias[g], bias[g], bias[g]};
            acch[g] = (f32x4){0.f, 0.f, 0.f, 0.f};
        }

        #pragma unroll
        for (int s = 0; s < 4; ++s) {
            const uint32_t ab =
                (uint32_t)(cl * 1024 + ((s * 64 + q * 16) ^ ((cl & 15) << 4)));
            const bf16x8 axh = *(const bf16x8*)&A[(ab >> 1)];
            const bf16x8 axl = *(const bf16x8*)&A[(ab >> 1) + 128];
            const bf16x8 ahh = *(const bf16x8*)&A[(ab >> 1) + 256];
            const bf16x8 ahl = *(const bf16x8*)&A[(ab >> 1) + 384];
            #pragma unroll
            for (int g = 0; g < 4; ++g) {
                const int col = g * NU + uu;
                const bf16x8 wkl = *(const bf16x8*)
                    &WKLO[(uint32_t)(col * 256 + ((s * 64 + q * 16) ^ ((col & 15) << 4))) >> 1];
                accx[g] = __builtin_amdgcn_mfma_f32_16x16x32_bf16(axh, wkh[g][s], accx[g], 0, 0, 0);
                accx[g] = __builtin_amdgcn_mfma_f32_16x16x32_bf16(axl, wkh[g][s], accx[g], 0, 0, 0);
                accx[g] = __builtin_amdgcn_mfma_f32_16x16x32_bf16(axh, wkl,       accx[g], 0, 0, 0);
                acch[g] = __builtin_amdgcn_mfma_f32_16x16x32_bf16(ahh, wrh[g][s], acch[g], 0, 0, 0);
                acch[g] = __builtin_amdgcn_mfma_f32_16x16x32_bf16(ahl, wrh[g][s], acch[g], 0, 0, 0);
                acch[g] = __builtin_amdgcn_mfma_f32_16x16x32_bf16(ahh, wrl[g][s], acch[g], 0, 0, 0);
            }
        }
        __syncthreads();   // sync2: frag reads done before h region is overwritten

        // gates + state; C/D layout: col = lane&15 (unit), row = q*4+j (batch row)
        #pragma unroll
        for (int j = 0; j < 4; ++j) {
            const int r = q * 4 + j;
            const float gi = sigm(accx[0][j] + acch[0][j]);
            const float gf = sigm(accx[1][j] + acch[1][j]);
            const float gg = tanh_fast(accx[2][j] + acch[2][j]);
            const float go = sigm(accx[3][j] + acch[3][j]);
            const float cn = gf * cc[j] + gi * gg;
            cc[j] = cn;
            const float h = go * tanh_fast(cn);
            const u16 hh = f2bf(h);
            const u16 hl = f2bf(h - bf2f(hh));
            const uint32_t hb = (uint32_t)(r * 1024 + ((2 * uu) ^ ((r & 15) << 4)));
            A[(hb >> 1) + 256] = hh;   // h_hi: k in [256,384)
            A[(hb >> 1) + 384] = hl;   // h_lo: k in [384,512)
            dst[(size_t)(base_b + r) * (NT * NU) + (size_t)t * NU + uu] = h;
        }
        // next step's sync1 orders these h writes vs reads and drains dst stores
    }

    __syncthreads();   // drain final step's dst stores
    if (PROD && tid == 0)
        __hip_atomic_store(prog_c, NT, __ATOMIC_RELEASE, __HIP_MEMORY_SCOPE_AGENT);
}

// grid = (64 groups, 2 dirs, 2 layers) = 256 blocks = 1 per CU (144 KiB LDS
// forces 1 block/CU, so all 256 are co-resident by capacity -> the consumer
// spin cannot deadlock: producers never wait on consumers).
__global__ __launch_bounds__(512, 2)
void lstm_scan(const float* __restrict__ x,
               const float* __restrict__ fwk, const float* __restrict__ fwrk,
               const float* __restrict__ fwb,
               const float* __restrict__ bwk, const float* __restrict__ bwrk,
               const float* __restrict__ bwb,
               float* __restrict__ buf_fw, float* __restrict__ buf_bw,
               int* __restrict__ prog) {
    extern __shared__ __align__(16) u16 smem[];
    u16* A    = smem;                 // [16][512] bf16, XOR-swizzled rows
    u16* WKLO = smem + LDS_A_ELEMS;   // [512 col][128 k] bf16, XOR-swizzled

    const int tid   = threadIdx.x;
    const int lane  = tid & 63;
    const int wv    = tid >> 6;         // wave 0..7
    const int grp   = blockIdx.x;       // 0..63
    const int dir   = blockIdx.y;       // 0 = fw, 1 = bw
    const int layer = blockIdx.z;       // 0 = producer, 1 = consumer
    const int base_b = grp * ROWS;

    const float* kp = dir ? bwk  : fwk;
    const float* rp = dir ? bwrk : fwrk;
    const float* bp = dir ? bwb  : fwb;
    float* buf = dir ? buf_bw : buf_fw;
    int* prog_c = prog + dir * 64 + grp;

    const int q  = lane >> 4;           // k-group 0..3
    const int cl = lane & 15;           // A-row / B-col within tile
    const int uu = (wv << 4) + cl;      // unit 0..127 owned by this lane

    const int sr = tid >> 5;            // staging row 0..15
    const int sc = (tid & 31) << 2;     // staging col 0..124

    if (layer == 0) {
        // layer 0: x -> buf (h0), publishing progress per step
        run_layer<true, false>(kp, rp, bp, x, buf, A, WKLO, prog_c,
                               dir, base_b, tid, q, cl, uu, sr, sc);
    } else {
        // layer 1: buf (h0) -> buf in-place (h1), gated on producer progress.
        // In-place safe: h0[t] is last read one step before h1[t] is written.
        run_layer<false, true>(kp + ND * NG, rp + NU * NG, bp + NG,
                               buf, buf, A, WKLO, prog_c,
                               dir, base_b, tid, q, cl, uu, sr, sc);
    }
}

// ---- merge: out = 0.5*(fw + bw) ---------------------------------------------
__global__ void merge_out(const float* __restrict__ a, const float* __restrict__ b,
                          float* __restrict__ o, int nvec) {
    int i = blockIdx.x * blockDim.x + threadIdx.x;
    const int st = gridDim.x * blockDim.x;
    for (; i < nvec; i += st) {
        const float4 va = ((const float4*)a)[i];
        const float4 vb = ((const float4*)b)[i];
        float4 r;
        r.x = 0.5f * (va.x + vb.x);
        r.y = 0.5f * (va.y + vb.y);
        r.z = 0.5f * (va.z + vb.z);
        r.w = 0.5f * (va.w + vb.w);
        ((float4*)o)[i] = r;
    }
}

extern "C" void kernel_launch(void* const* d_in, const int* in_sizes, int n_in,
                              void* d_out, int out_size, void* d_ws, size_t ws_size,
                              hipStream_t stream) {
    const float* x    = (const float*)d_in[0];
    const float* fwk  = (const float*)d_in[1];
    const float* fwrk = (const float*)d_in[2];
    const float* fwb  = (const float*)d_in[3];
    const float* bwk  = (const float*)d_in[4];
    const float* bwrk = (const float*)d_in[5];
    const float* bwb  = (const float*)d_in[6];
    float* out = (float*)d_out;

    const size_t seq = (size_t)NB * NT * NU;     // 26,214,400 elements
    float* buf_fw = (float*)d_ws;                // fw chain h (h0 then h1 in-place)
    float* buf_bw = buf_fw + seq;                // bw chain h
    int*   prog   = (int*)(buf_bw + seq);        // 128 per-chain progress counters

    // progress counters must be zero at every launch (deterministic replay)
    hipMemsetAsync(prog, 0, 128 * sizeof(int), stream);

    const size_t lds_bytes = (size_t)(LDS_A_ELEMS + LDS_WK_ELEMS) * sizeof(u16); // 147456
    (void)hipFuncSetAttribute((const void*)lstm_scan,
                              hipFuncAttributeMaxDynamicSharedMemorySize,
                              (int)lds_bytes);

    lstm_scan<<<dim3(64, 2, 2), 512, lds_bytes, stream>>>(
        x, fwk, fwrk, fwb, bwk, bwrk, bwb, buf_fw, buf_bw, prog);

    const int nvec = (int)(seq / 4);
    merge_out<<<2048, 256, 0, stream>>>(buf_fw, buf_bw, out, nvec);
}

// Round 8
// 1582.715 us; speedup vs baseline: 3.8112x; 1.6699x over previous
//
#include <hip/hip_runtime.h>
#include <cstdint>

typedef unsigned short u16;
typedef __attribute__((ext_vector_type(4))) float f32x4;
typedef __attribute__((ext_vector_type(8))) short bf16x8;   // 8 bf16 in 4 VGPRs
typedef __attribute__((ext_vector_type(4))) u16 u16x4;

constexpr int NB = 1024;   // batch
constexpr int NT = 200;    // time
constexpr int ND = 128;    // input dim
constexpr int NU = 128;    // units
constexpr int NG = 512;    // 4*U gates
constexpr int ROWS = 16;   // batch rows per block (MFMA M)
constexpr int CHUNK = 8;   // pipeline handshake granularity (divides NT)
constexpr int LDS_A_ELEMS  = ROWS * 512;  // 8192 u16 = 16 KiB
constexpr int LDS_WK_ELEMS = NG * ND;     // 65536 u16 = 128 KiB (Wk_lo, [col][k])

__device__ __forceinline__ u16 f2bf(float x) {
    uint32_t u = __builtin_bit_cast(uint32_t, x);
    u = (u + 0x7fffu + ((u >> 16) & 1u)) >> 16;   // RNE
    return (u16)u;
}
__device__ __forceinline__ float bf2f(u16 b) {
    uint32_t u = ((uint32_t)b) << 16;
    return __builtin_bit_cast(float, u);
}
__device__ __forceinline__ float sigm(float x) {
    return __builtin_amdgcn_rcpf(1.f + __expf(-x));
}
__device__ __forceinline__ float tanh_fast(float x) {
    float e = __expf(-2.f * fabsf(x));
    float t = (1.f - e) * __builtin_amdgcn_rcpf(1.f + e);
    return copysignf(t, x);
}

__device__ __forceinline__ void spin_until(const int* p, int need) {
    while (__hip_atomic_load(p, __ATOMIC_ACQUIRE, __HIP_MEMORY_SCOPE_AGENT) < need)
        __builtin_amdgcn_s_sleep(8);
}

// One LSTM layer scan for 16 batch rows (r3-proven core: 3 register weight
// arrays — the compiler register-hosts exactly 3; a 4th forces global
// rematerialization (r6: FETCH 25x) — plus Wk_lo in LDS).
// PROD: publish per-chunk progress (layer 0). CONS: gate x-loads on producer
// progress — tid0-only poll + barrier broadcast, once per CHUNK steps
// (r7 lesson: all-thread polling = agent-scope atomic storm, 2.6x slowdown).
template<bool PROD, bool CONS>
__device__ __forceinline__ void run_layer(
    const float* __restrict__ Wk, const float* __restrict__ Wr,
    const float* __restrict__ Bv,
    const float* __restrict__ src, float* __restrict__ dst,
    u16* A, u16* WKLO, int* prog_c,
    const int dir, const int base_b,
    const int tid, const int q, const int cl, const int uu,
    const int sr, const int sc)
{
    // ---- resident weight fragments (B-side): Wk_hi, Wr_hi, Wr_lo
    bf16x8 wkh[4][4], wrh[4][4], wrl[4][4];
    #pragma unroll
    for (int g = 0; g < 4; ++g) {
        const int col = g * NU + uu;
        #pragma unroll
        for (int s = 0; s < 4; ++s) {
            bf16x8 fa, fh, fl;
            #pragma unroll
            for (int j = 0; j < 8; ++j) {
                const int k = s * 32 + q * 8 + j;
                fa[j] = (short)f2bf(Wk[k * NG + col]);
                const float w = Wr[k * NG + col];
                const u16 hi = f2bf(w);
                fh[j] = (short)hi;
                fl[j] = (short)f2bf(w - bf2f(hi));
            }
            wkh[g][s] = fa; wrh[g][s] = fh; wrl[g][s] = fl;
        }
    }
    float bias[4];
    #pragma unroll
    for (int g = 0; g < 4; ++g) bias[g] = Bv[g * NU + uu];

    // fill Wk_lo into LDS (transposed [col][k], swizzled)
    for (int idx = tid; idx < LDS_WK_ELEMS; idx += 512) {
        const int col = idx & (NG - 1);
        const int k   = idx >> 9;
        const float w = Wk[k * NG + col];
        const float lo = w - bf2f(f2bf(w));
        WKLO[(uint32_t)(col * 256 + ((2 * k) ^ ((col & 15) << 4))) >> 1] = f2bf(lo);
    }
    for (int i = tid; i < LDS_A_ELEMS; i += 512) A[i] = 0;   // h planes must be 0
    f32x4 cc = {0.f, 0.f, 0.f, 0.f};

    const size_t srow = (size_t)(base_b + sr) * (NT * NU) + sc;

    if (CONS && tid == 0) spin_until(prog_c, 2);   // x_{t(0)} available (even-rounded)
    __syncthreads();   // WKLO+zero visible; spin result broadcast
    float4 cur = *(const float4*)&src[srow + (size_t)(dir ? NT - 1 : 0) * NU];

    for (int cs = 0; cs < NT; cs += CHUNK) {
        // gate the whole chunk: steps cs..cs+7 load x_{cs+1}..x_{cs+8},
        // needing prog >= cs+9 (round to even publish grid -> cs+10)
        if (CONS) {
            if (tid == 0) {
                const int need = (cs + CHUNK + 2 < NT) ? cs + CHUNK + 2 : NT;
                spin_until(prog_c, need);
            }
            __syncthreads();
        }

        for (int step = cs; step < cs + CHUNK; ++step) {
            const int t = dir ? (NT - 1 - step) : step;

            // ---- stage x_t (in regs) as hi+lo into A's k<256 half
            {
                const float vv[4] = {cur.x, cur.y, cur.z, cur.w};
                u16x4 hi4, lo4;
                #pragma unroll
                for (int e = 0; e < 4; ++e) {
                    const u16 h = f2bf(vv[e]);
                    hi4[e] = h;
                    lo4[e] = f2bf(vv[e] - bf2f(h));
                }
                const uint32_t b0 = (uint32_t)(sr * 1024 + ((2 * sc) ^ ((sr & 15) << 4)));
                *(u16x4*)&A[(b0 >> 1)]       = hi4;   // x_hi: k in [0,128)
                *(u16x4*)&A[(b0 >> 1) + 128] = lo4;   // x_lo: k in [128,256)
            }
            __syncthreads();   // sync1: staging visible; all waves' older stores drained

            // publish every 2nd step: steps 0..step-1 are drained by sync1
            if (PROD && tid == 0 && (step & 1) == 0 && step)
                __hip_atomic_store(prog_c, step, __ATOMIC_RELEASE, __HIP_MEMORY_SCOPE_AGENT);

            // prefetch x_{t(step+1)}: used at next step's staging (chunk-gated)
            if (step + 1 < NT) {
                const int tn = dir ? (NT - 2 - step) : (step + 1);
                cur = *(const float4*)&src[srow + (size_t)tn * NU];
            }

            f32x4 accx[4], acch[4];   // x-side (carries bias) and h-side chains
            #pragma unroll
            for (int g = 0; g < 4; ++g) {
                accx[g] = (f32x4){bias[g], bias[g], bias[g], bias[g]};
                acch[g] = (f32x4){0.f, 0.f, 0.f, 0.f};
            }

            #pragma unroll
            for (int s = 0; s < 4; ++s) {
                const uint32_t ab =
                    (uint32_t)(cl * 1024 + ((s * 64 + q * 16) ^ ((cl & 15) << 4)));
                const bf16x8 axh = *(const bf16x8*)&A[(ab >> 1)];
                const bf16x8 axl = *(const bf16x8*)&A[(ab >> 1) + 128];
                const bf16x8 ahh = *(const bf16x8*)&A[(ab >> 1) + 256];
                const bf16x8 ahl = *(const bf16x8*)&A[(ab >> 1) + 384];
                #pragma unroll
                for (int g = 0; g < 4; ++g) {
                    const int col = g * NU + uu;
                    const bf16x8 wkl = *(const bf16x8*)
                        &WKLO[(uint32_t)(col * 256 + ((s * 64 + q * 16) ^ ((col & 15) << 4))) >> 1];
                    accx[g] = __builtin_amdgcn_mfma_f32_16x16x32_bf16(axh, wkh[g][s], accx[g], 0, 0, 0);
                    accx[g] = __builtin_amdgcn_mfma_f32_16x16x32_bf16(axl, wkh[g][s], accx[g], 0, 0, 0);
                    accx[g] = __builtin_amdgcn_mfma_f32_16x16x32_bf16(axh, wkl,       accx[g], 0, 0, 0);
                    acch[g] = __builtin_amdgcn_mfma_f32_16x16x32_bf16(ahh, wrh[g][s], acch[g], 0, 0, 0);
                    acch[g] = __builtin_amdgcn_mfma_f32_16x16x32_bf16(ahl, wrh[g][s], acch[g], 0, 0, 0);
                    acch[g] = __builtin_amdgcn_mfma_f32_16x16x32_bf16(ahh, wrl[g][s], acch[g], 0, 0, 0);
                }
            }
            __syncthreads();   // sync2: frag reads done before h region is overwritten

            // gates + state; C/D layout: col = lane&15 (unit), row = q*4+j
            #pragma unroll
            for (int j = 0; j < 4; ++j) {
                const int r = q * 4 + j;
                const float gi = sigm(accx[0][j] + acch[0][j]);
                const float gf = sigm(accx[1][j] + acch[1][j]);
                const float gg = tanh_fast(accx[2][j] + acch[2][j]);
                const float go = sigm(accx[3][j] + acch[3][j]);
                const float cn = gf * cc[j] + gi * gg;
                cc[j] = cn;
                const float h = go * tanh_fast(cn);
                const u16 hh = f2bf(h);
                const u16 hl = f2bf(h - bf2f(hh));
                const uint32_t hb = (uint32_t)(r * 1024 + ((2 * uu) ^ ((r & 15) << 4)));
                A[(hb >> 1) + 256] = hh;   // h_hi: k in [256,384)
                A[(hb >> 1) + 384] = hl;   // h_lo: k in [384,512)
                dst[(size_t)(base_b + r) * (NT * NU) + (size_t)t * NU + uu] = h;
            }
            // next step's sync1 orders these h writes vs reads, drains dst stores
        }
    }

    __syncthreads();   // drain final step's dst stores
    if (PROD && tid == 0)
        __hip_atomic_store(prog_c, NT, __ATOMIC_RELEASE, __HIP_MEMORY_SCOPE_AGENT);
}

// grid = (64 groups, 2 dirs, 2 layers) = 256 blocks = 1 per CU (144 KiB LDS
// forces 1 block/CU, so all 256 are co-resident by capacity -> the consumer
// spin cannot deadlock: producers never wait on consumers).
__global__ __launch_bounds__(512, 2)
void lstm_scan(const float* __restrict__ x,
               const float* __restrict__ fwk, const float* __restrict__ fwrk,
               const float* __restrict__ fwb,
               const float* __restrict__ bwk, const float* __restrict__ bwrk,
               const float* __restrict__ bwb,
               float* __restrict__ buf_fw, float* __restrict__ buf_bw,
               int* __restrict__ prog) {
    extern __shared__ __align__(16) u16 smem[];
    u16* A    = smem;                 // [16][512] bf16, XOR-swizzled rows
    u16* WKLO = smem + LDS_A_ELEMS;   // [512 col][128 k] bf16, XOR-swizzled

    const int tid   = threadIdx.x;
    const int lane  = tid & 63;
    const int wv    = tid >> 6;         // wave 0..7
    const int grp   = blockIdx.x;       // 0..63
    const int dir   = blockIdx.y;       // 0 = fw, 1 = bw
    const int layer = blockIdx.z;       // 0 = producer, 1 = consumer
    const int base_b = grp * ROWS;

    const float* kp = dir ? bwk  : fwk;
    const float* rp = dir ? bwrk : fwrk;
    const float* bp = dir ? bwb  : fwb;
    float* buf = dir ? buf_bw : buf_fw;
    int* prog_c = prog + dir * 64 + grp;

    const int q  = lane >> 4;           // k-group 0..3
    const int cl = lane & 15;           // A-row / B-col within tile
    const int uu = (wv << 4) + cl;      // unit 0..127 owned by this lane

    const int sr = tid >> 5;            // staging row 0..15
    const int sc = (tid & 31) << 2;     // staging col 0..124

    if (layer == 0) {
        // layer 0: x -> buf (h0), publishing progress
        run_layer<true, false>(kp, rp, bp, x, buf, A, WKLO, prog_c,
                               dir, base_b, tid, q, cl, uu, sr, sc);
    } else {
        // layer 1: buf (h0) -> buf in-place (h1), gated on producer progress.
        // In-place safe: h0[t] is last read one step before h1[t] is written.
        run_layer<false, true>(kp + ND * NG, rp + NU * NG, bp + NG,
                               buf, buf, A, WKLO, prog_c,
                               dir, base_b, tid, q, cl, uu, sr, sc);
    }
}

// ---- merge: out = 0.5*(fw + bw) ---------------------------------------------
__global__ void merge_out(const float* __restrict__ a, const float* __restrict__ b,
                          float* __restrict__ o, int nvec) {
    int i = blockIdx.x * blockDim.x + threadIdx.x;
    const int st = gridDim.x * blockDim.x;
    for (; i < nvec; i += st) {
        const float4 va = ((const float4*)a)[i];
        const float4 vb = ((const float4*)b)[i];
        float4 r;
        r.x = 0.5f * (va.x + vb.x);
        r.y = 0.5f * (va.y + vb.y);
        r.z = 0.5f * (va.z + vb.z);
        r.w = 0.5f * (va.w + vb.w);
        ((float4*)o)[i] = r;
    }
}

extern "C" void kernel_launch(void* const* d_in, const int* in_sizes, int n_in,
                              void* d_out, int out_size, void* d_ws, size_t ws_size,
                              hipStream_t stream) {
    const float* x    = (const float*)d_in[0];
    const float* fwk  = (const float*)d_in[1];
    const float* fwrk = (const float*)d_in[2];
    const float* fwb  = (const float*)d_in[3];
    const float* bwk  = (const float*)d_in[4];
    const float* bwrk = (const float*)d_in[5];
    const float* bwb  = (const float*)d_in[6];
    float* out = (float*)d_out;

    const size_t seq = (size_t)NB * NT * NU;     // 26,214,400 elements
    float* buf_fw = (float*)d_ws;                // fw chain h (h0 then h1 in-place)
    float* buf_bw = buf_fw + seq;                // bw chain h
    int*   prog   = (int*)(buf_bw + seq);        // 128 per-chain progress counters

    // progress counters must be zero at every launch (deterministic replay)
    hipMemsetAsync(prog, 0, 128 * sizeof(int), stream);

    const size_t lds_bytes = (size_t)(LDS_A_ELEMS + LDS_WK_ELEMS) * sizeof(u16); // 147456
    (void)hipFuncSetAttribute((const void*)lstm_scan,
                              hipFuncAttributeMaxDynamicSharedMemorySize,
                              (int)lds_bytes);

    lstm_scan<<<dim3(64, 2, 2), 512, lds_bytes, stream>>>(
        x, fwk, fwrk, fwb, bwk, bwrk, bwb, buf_fw, buf_bw, prog);

    const int nvec = (int)(seq / 4);
    merge_out<<<2048, 256, 0, stream>>>(buf_fw, buf_bw, out, nvec);
}

// Round 9
// 1236.542 us; speedup vs baseline: 4.8782x; 1.2800x over previous
//
#include <hip/hip_runtime.h>
#include <cstdint>

typedef unsigned short u16;
typedef __attribute__((ext_vector_type(4))) float f32x4;
typedef __attribute__((ext_vector_type(8))) short bf16x8;   // 8 bf16 in 4 VGPRs
typedef __attribute__((ext_vector_type(4))) u16 u16x4;

constexpr int NB = 1024;   // batch
constexpr int NT = 200;    // time
constexpr int ND = 128;    // input dim
constexpr int NU = 128;    // units
constexpr int NG = 512;    // 4*U gates
constexpr int ROWS = 16;   // batch rows per block (MFMA M)
constexpr int CHUNK = 8;   // pipeline handshake granularity (divides NT)
constexpr int LDS_A_ELEMS  = ROWS * 512;  // 8192 u16 = 16 KiB
constexpr int LDS_WK_ELEMS = NG * ND;     // 65536 u16 = 128 KiB (Wk_lo, [col][k])

__device__ __forceinline__ u16 f2bf(float x) {
    uint32_t u = __builtin_bit_cast(uint32_t, x);
    u = (u + 0x7fffu + ((u >> 16) & 1u)) >> 16;   // RNE
    return (u16)u;
}
__device__ __forceinline__ float bf2f(u16 b) {
    uint32_t u = ((uint32_t)b) << 16;
    return __builtin_bit_cast(float, u);
}
__device__ __forceinline__ float sigm(float x) {
    return __builtin_amdgcn_rcpf(1.f + __expf(-x));
}
__device__ __forceinline__ float tanh_fast(float x) {
    float e = __expf(-2.f * fabsf(x));
    float t = (1.f - e) * __builtin_amdgcn_rcpf(1.f + e);
    return copysignf(t, x);
}

// Poll RELAXED (plain coherence-point load, NO buffer_inv), then ONE acquire
// re-read for the synchronizes-with edge. r8 lesson: ACQUIRE in the poll loop
// = whole-L2 buffer_inv every ~500cyc -> TCC tag-walk thrash, +80%/step.
__device__ __forceinline__ void spin_gate(const int* p, int need) {
    while (__hip_atomic_load(p, __ATOMIC_RELAXED, __HIP_MEMORY_SCOPE_AGENT) < need)
        __builtin_amdgcn_s_sleep(16);
    (void)__hip_atomic_load(p, __ATOMIC_ACQUIRE, __HIP_MEMORY_SCOPE_AGENT);
}

// One LSTM layer scan for 16 batch rows (r3-proven core: 3 register weight
// arrays — a 4th exceeds the 256-VGPR cap and forces global rematerialization
// (r6: FETCH 25x) — plus Wk_lo in LDS).
// PROD publishes progress at CHUNK boundaries (release, 25 fences/layer);
// CONS gates once per CHUNK (1 acquire each). Chains (dir,grp) independent.
template<bool PROD, bool CONS>
__device__ __forceinline__ void run_layer(
    const float* __restrict__ Wk, const float* __restrict__ Wr,
    const float* __restrict__ Bv,
    const float* __restrict__ src, float* __restrict__ dst,
    u16* A, u16* WKLO, int* prog_c,
    const int dir, const int base_b,
    const int tid, const int q, const int cl, const int uu,
    const int sr, const int sc)
{
    // ---- resident weight fragments (B-side): Wk_hi, Wr_hi, Wr_lo
    bf16x8 wkh[4][4], wrh[4][4], wrl[4][4];
    #pragma unroll
    for (int g = 0; g < 4; ++g) {
        const int col = g * NU + uu;
        #pragma unroll
        for (int s = 0; s < 4; ++s) {
            bf16x8 fa, fh, fl;
            #pragma unroll
            for (int j = 0; j < 8; ++j) {
                const int k = s * 32 + q * 8 + j;
                fa[j] = (short)f2bf(Wk[k * NG + col]);
                const float w = Wr[k * NG + col];
                const u16 hi = f2bf(w);
                fh[j] = (short)hi;
                fl[j] = (short)f2bf(w - bf2f(hi));
            }
            wkh[g][s] = fa; wrh[g][s] = fh; wrl[g][s] = fl;
        }
    }
    float bias[4];
    #pragma unroll
    for (int g = 0; g < 4; ++g) bias[g] = Bv[g * NU + uu];

    // fill Wk_lo into LDS (transposed [col][k], swizzled)
    for (int idx = tid; idx < LDS_WK_ELEMS; idx += 512) {
        const int col = idx & (NG - 1);
        const int k   = idx >> 9;
        const float w = Wk[k * NG + col];
        const float lo = w - bf2f(f2bf(w));
        WKLO[(uint32_t)(col * 256 + ((2 * k) ^ ((col & 15) << 4))) >> 1] = f2bf(lo);
    }
    for (int i = tid; i < LDS_A_ELEMS; i += 512) A[i] = 0;   // h planes must be 0
    f32x4 cc = {0.f, 0.f, 0.f, 0.f};

    const size_t srow = (size_t)(base_b + sr) * (NT * NU) + sc;

    // pre-loop gate: x_{t(0)} needs prog >= 1 -> round up to publish grid
    if (CONS && tid == 0) spin_gate(prog_c, (2 * CHUNK < NT) ? 2 * CHUNK : NT);
    __syncthreads();   // WKLO+zero visible; gate result broadcast
    float4 cur = *(const float4*)&src[srow + (size_t)(dir ? NT - 1 : 0) * NU];

    for (int cs = 0; cs < NT; cs += CHUNK) {
        // gate chunk cs: steps cs..cs+7 prefetch x_{cs+1}..x_{cs+8}, needing
        // prog >= cs+9 -> rounded to the CHUNK publish grid = cs+16
        if (CONS && cs > 0) {
            if (tid == 0) {
                const int need = (cs + 2 * CHUNK < NT) ? cs + 2 * CHUNK : NT;
                spin_gate(prog_c, need);
            }
            __syncthreads();
        }

        for (int step = cs; step < cs + CHUNK; ++step) {
            const int t = dir ? (NT - 1 - step) : step;

            // ---- stage x_t (in regs) as hi+lo into A's k<256 half
            {
                const float vv[4] = {cur.x, cur.y, cur.z, cur.w};
                u16x4 hi4, lo4;
                #pragma unroll
                for (int e = 0; e < 4; ++e) {
                    const u16 h = f2bf(vv[e]);
                    hi4[e] = h;
                    lo4[e] = f2bf(vv[e] - bf2f(h));
                }
                const uint32_t b0 = (uint32_t)(sr * 1024 + ((2 * sc) ^ ((sr & 15) << 4)));
                *(u16x4*)&A[(b0 >> 1)]       = hi4;   // x_hi: k in [0,128)
                *(u16x4*)&A[(b0 >> 1) + 128] = lo4;   // x_lo: k in [128,256)
            }
            __syncthreads();   // sync1: staging visible; all waves' older stores drained

            // publish at chunk boundaries only: steps 0..step-1 drained by sync1
            if (PROD && tid == 0 && step && (step & (CHUNK - 1)) == 0)
                __hip_atomic_store(prog_c, step, __ATOMIC_RELEASE, __HIP_MEMORY_SCOPE_AGENT);

            // prefetch x_{t(step+1)}: used at next step's staging (chunk-gated)
            if (step + 1 < NT) {
                const int tn = dir ? (NT - 2 - step) : (step + 1);
                cur = *(const float4*)&src[srow + (size_t)tn * NU];
            }

            f32x4 accx[4], acch[4];   // x-side (carries bias) and h-side chains
            #pragma unroll
            for (int g = 0; g < 4; ++g) {
                accx[g] = (f32x4){bias[g], bias[g], bias[g], bias[g]};
                acch[g] = (f32x4){0.f, 0.f, 0.f, 0.f};
            }

            #pragma unroll
            for (int s = 0; s < 4; ++s) {
                const uint32_t ab =
                    (uint32_t)(cl * 1024 + ((s * 64 + q * 16) ^ ((cl & 15) << 4)));
                const bf16x8 axh = *(const bf16x8*)&A[(ab >> 1)];
                const bf16x8 axl = *(const bf16x8*)&A[(ab >> 1) + 128];
                const bf16x8 ahh = *(const bf16x8*)&A[(ab >> 1) + 256];
                const bf16x8 ahl = *(const bf16x8*)&A[(ab >> 1) + 384];
                #pragma unroll
                for (int g = 0; g < 4; ++g) {
                    const int col = g * NU + uu;
                    const bf16x8 wkl = *(const bf16x8*)
                        &WKLO[(uint32_t)(col * 256 + ((s * 64 + q * 16) ^ ((col & 15) << 4))) >> 1];
                    accx[g] = __builtin_amdgcn_mfma_f32_16x16x32_bf16(axh, wkh[g][s], accx[g], 0, 0, 0);
                    accx[g] = __builtin_amdgcn_mfma_f32_16x16x32_bf16(axl, wkh[g][s], accx[g], 0, 0, 0);
                    accx[g] = __builtin_amdgcn_mfma_f32_16x16x32_bf16(axh, wkl,       accx[g], 0, 0, 0);
                    acch[g] = __builtin_amdgcn_mfma_f32_16x16x32_bf16(ahh, wrh[g][s], acch[g], 0, 0, 0);
                    acch[g] = __builtin_amdgcn_mfma_f32_16x16x32_bf16(ahl, wrh[g][s], acch[g], 0, 0, 0);
                    acch[g] = __builtin_amdgcn_mfma_f32_16x16x32_bf16(ahh, wrl[g][s], acch[g], 0, 0, 0);
                }
            }
            __syncthreads();   // sync2: frag reads done before h region is overwritten

            // gates + state; C/D layout: col = lane&15 (unit), row = q*4+j
            #pragma unroll
            for (int j = 0; j < 4; ++j) {
                const int r = q * 4 + j;
                const float gi = sigm(accx[0][j] + acch[0][j]);
                const float gf = sigm(accx[1][j] + acch[1][j]);
                const float gg = tanh_fast(accx[2][j] + acch[2][j]);
                const float go = sigm(accx[3][j] + acch[3][j]);
                const float cn = gf * cc[j] + gi * gg;
                cc[j] = cn;
                const float h = go * tanh_fast(cn);
                const u16 hh = f2bf(h);
                const u16 hl = f2bf(h - bf2f(hh));
                const uint32_t hb = (uint32_t)(r * 1024 + ((2 * uu) ^ ((r & 15) << 4)));
                A[(hb >> 1) + 256] = hh;   // h_hi: k in [256,384)
                A[(hb >> 1) + 384] = hl;   // h_lo: k in [384,512)
                dst[(size_t)(base_b + r) * (NT * NU) + (size_t)t * NU + uu] = h;
            }
            // next step's sync1 orders these h writes vs reads, drains dst stores
        }
    }

    __syncthreads();   // drain final step's dst stores
    if (PROD && tid == 0)
        __hip_atomic_store(prog_c, NT, __ATOMIC_RELEASE, __HIP_MEMORY_SCOPE_AGENT);
}

// grid = (64 groups, 2 dirs, 2 layers) = 256 blocks = 1 per CU (144 KiB LDS
// forces 1 block/CU, so all 256 are co-resident by capacity -> the consumer
// spin cannot deadlock: producers never wait on consumers).
__global__ __launch_bounds__(512, 2)
void lstm_scan(const float* __restrict__ x,
               const float* __restrict__ fwk, const float* __restrict__ fwrk,
               const float* __restrict__ fwb,
               const float* __restrict__ bwk, const float* __restrict__ bwrk,
               const float* __restrict__ bwb,
               float* __restrict__ buf_fw, float* __restrict__ buf_bw,
               int* __restrict__ prog) {
    extern __shared__ __align__(16) u16 smem[];
    u16* A    = smem;                 // [16][512] bf16, XOR-swizzled rows
    u16* WKLO = smem + LDS_A_ELEMS;   // [512 col][128 k] bf16, XOR-swizzled

    const int tid   = threadIdx.x;
    const int lane  = tid & 63;
    const int wv    = tid >> 6;         // wave 0..7
    const int grp   = blockIdx.x;       // 0..63
    const int dir   = blockIdx.y;       // 0 = fw, 1 = bw
    const int layer = blockIdx.z;       // 0 = producer, 1 = consumer
    const int base_b = grp * ROWS;

    const float* kp = dir ? bwk  : fwk;
    const float* rp = dir ? bwrk : fwrk;
    const float* bp = dir ? bwb  : fwb;
    float* buf = dir ? buf_bw : buf_fw;
    int* prog_c = prog + dir * 64 + grp;

    const int q  = lane >> 4;           // k-group 0..3
    const int cl = lane & 15;           // A-row / B-col within tile
    const int uu = (wv << 4) + cl;      // unit 0..127 owned by this lane

    const int sr = tid >> 5;            // staging row 0..15
    const int sc = (tid & 31) << 2;     // staging col 0..124

    if (layer == 0) {
        // layer 0: x -> buf (h0), publishing progress
        run_layer<true, false>(kp, rp, bp, x, buf, A, WKLO, prog_c,
                               dir, base_b, tid, q, cl, uu, sr, sc);
    } else {
        // layer 1: buf (h0) -> buf in-place (h1), gated on producer progress.
        // In-place safe: h0[t] is last read one step before h1[t] is written.
        run_layer<false, true>(kp + ND * NG, rp + NU * NG, bp + NG,
                               buf, buf, A, WKLO, prog_c,
                               dir, base_b, tid, q, cl, uu, sr, sc);
    }
}

// ---- merge: out = 0.5*(fw + bw) ---------------------------------------------
__global__ void merge_out(const float* __restrict__ a, const float* __restrict__ b,
                          float* __restrict__ o, int nvec) {
    int i = blockIdx.x * blockDim.x + threadIdx.x;
    const int st = gridDim.x * blockDim.x;
    for (; i < nvec; i += st) {
        const float4 va = ((const float4*)a)[i];
        const float4 vb = ((const float4*)b)[i];
        float4 r;
        r.x = 0.5f * (va.x + vb.x);
        r.y = 0.5f * (va.y + vb.y);
        r.z = 0.5f * (va.z + vb.z);
        r.w = 0.5f * (va.w + vb.w);
        ((float4*)o)[i] = r;
    }
}

extern "C" void kernel_launch(void* const* d_in, const int* in_sizes, int n_in,
                              void* d_out, int out_size, void* d_ws, size_t ws_size,
                              hipStream_t stream) {
    const float* x    = (const float*)d_in[0];
    const float* fwk  = (const float*)d_in[1];
    const float* fwrk = (const float*)d_in[2];
    const float* fwb  = (const float*)d_in[3];
    const float* bwk  = (const float*)d_in[4];
    const float* bwrk = (const float*)d_in[5];
    const float* bwb  = (const float*)d_in[6];
    float* out = (float*)d_out;

    const size_t seq = (size_t)NB * NT * NU;     // 26,214,400 elements
    float* buf_fw = (float*)d_ws;                // fw chain h (h0 then h1 in-place)
    float* buf_bw = buf_fw + seq;                // bw chain h
    int*   prog   = (int*)(buf_bw + seq);        // 128 per-chain progress counters

    // progress counters must be zero at every launch (deterministic replay)
    hipMemsetAsync(prog, 0, 128 * sizeof(int), stream);

    const size_t lds_bytes = (size_t)(LDS_A_ELEMS + LDS_WK_ELEMS) * sizeof(u16); // 147456
    (void)hipFuncSetAttribute((const void*)lstm_scan,
                              hipFuncAttributeMaxDynamicSharedMemorySize,
                              (int)lds_bytes);

    lstm_scan<<<dim3(64, 2, 2), 512, lds_bytes, stream>>>(
        x, fwk, fwrk, fwb, bwk, bwrk, bwb, buf_fw, buf_bw, prog);

    const int nvec = (int)(seq / 4);
    merge_out<<<2048, 256, 0, stream>>>(buf_fw, buf_bw, out, nvec);
}